// Round 12
// baseline (61.439 us; speedup 1.0000x reference)
//
#include <hip/hip_runtime.h>

typedef unsigned short u16;
typedef __attribute__((ext_vector_type(4))) float f32x4;
typedef __attribute__((ext_vector_type(8))) short bf16x8;
typedef __attribute__((ext_vector_type(4))) u16 u16x4;

#define MFMA(a, b, c) __builtin_amdgcn_mfma_f32_16x16x32_bf16(a, b, c, 0, 0, 0)

__device__ __forceinline__ u16 f2bf(float f) {
    unsigned u = __float_as_uint(f);
    u += 0x7fffu + ((u >> 16) & 1u);   // round-to-nearest-even
    return (u16)(u >> 16);
}
__device__ __forceinline__ float bf2f(u16 h) {
    unsigned u = ((unsigned)h) << 16;
    return __uint_as_float(u);
}

__device__ __forceinline__ void load_lds16(const void* g, void* l) {
    __builtin_amdgcn_global_load_lds((const __attribute__((address_space(1))) void*)g,
                                     (__attribute__((address_space(3))) void*)l,
                                     16, 0, 0);
}

// ---------------------------------------------------------------------------
// Kernel 1: pack Wq|Wk|Wv (fp32 [1024][64]) -> Wtt bf16, tile-major + swizzled.
// ---------------------------------------------------------------------------
__global__ void wt_pack(const float* __restrict__ Wq, const float* __restrict__ Wk,
                        const float* __restrict__ Wv, u16* __restrict__ Wtt) {
    const int k = blockIdx.x;        // 0..1023
    const int n = threadIdx.x;       // 0..191
    const float* W = (n < 64) ? Wq : (n < 128 ? Wk : Wv);
    const float v = W[(size_t)k * 64 + (n & 63)];
    const int kt = k >> 6, ks = k & 63, c = ks >> 3, ci = ks & 7;
    Wtt[(size_t)kt * 12288 + n * 64 + (((c ^ (n & 7)) << 3) + ci)] = f2bf(v);
}

// ---------------------------------------------------------------------------
// Kernel 2: qkv projection, m97-structure, BM=32 / 4 waves / 512 blocks.
// Q output pre-scaled by log2(e)/sqrt(1024). (Best-known config, unchanged.)
// ---------------------------------------------------------------------------
__global__ __launch_bounds__(256, 2) void qkv_gemm(const float* __restrict__ x,
                                                   const u16* __restrict__ Wtt,
                                                   u16* __restrict__ qo,
                                                   u16* __restrict__ ko,
                                                   u16* __restrict__ vT) {
    const int tid = threadIdx.x;
    const int lane = tid & 63, wave = tid >> 6;
    const int lr = lane & 15, lg = lane >> 4;
    const int m0 = blockIdx.x * 32;

    __shared__ __align__(16) float xs[2][32 * 64];
    __shared__ __align__(16) u16 ws[2][192 * 64];

    f32x4 acc[2][3];
#pragma unroll
    for (int m = 0; m < 2; ++m)
#pragma unroll
        for (int n = 0; n < 3; ++n) acc[m][n] = (f32x4){0.f, 0.f, 0.f, 0.f};

    const int srow = tid >> 4;
    const int schk = tid & 15;

    {
#pragma unroll
        for (int j = 0; j < 2; ++j) {
            const int rr = j * 16 + srow;
            const float* src = x + (size_t)(m0 + rr) * 1024 + ((schk ^ (rr & 7)) << 2);
            load_lds16(src, &xs[0][j * 1024 + wave * 256]);
        }
#pragma unroll
        for (int j = 0; j < 6; ++j) {
            const u16* src = Wtt + (size_t)j * 2048 + tid * 8;
            load_lds16(src, &ws[0][j * 2048 + wave * 512]);
        }
    }
    __syncthreads();

    for (int kt = 0; kt < 16; ++kt) {
        const int cur = kt & 1;
        if (kt < 15) {
            const int nxt = cur ^ 1;
#pragma unroll
            for (int j = 0; j < 2; ++j) {
                const int rr = j * 16 + srow;
                const float* src =
                    x + (size_t)(m0 + rr) * 1024 + (kt + 1) * 64 + ((schk ^ (rr & 7)) << 2);
                load_lds16(src, &xs[nxt][j * 1024 + wave * 256]);
            }
#pragma unroll
            for (int j = 0; j < 6; ++j) {
                const u16* src = Wtt + (size_t)(kt + 1) * 12288 + j * 2048 + tid * 8;
                load_lds16(src, &ws[nxt][j * 2048 + wave * 512]);
            }
        }
#pragma unroll
        for (int h = 0; h < 2; ++h) {
            bf16x8 a[2];
#pragma unroll
            for (int mm = 0; mm < 2; ++mm) {
                const int rr = mm * 16 + lr;
                const int c0 = h * 8 + lg * 2;
                f32x4 f0 = *(const f32x4*)&xs[cur][rr * 64 + ((c0 ^ (rr & 7)) << 2)];
                f32x4 f1 = *(const f32x4*)&xs[cur][rr * 64 + (((c0 + 1) ^ (rr & 7)) << 2)];
                bf16x8 t;
#pragma unroll
                for (int i = 0; i < 4; ++i) {
                    t[i] = (short)f2bf(f0[i]);
                    t[i + 4] = (short)f2bf(f1[i]);
                }
                a[mm] = t;
            }
#pragma unroll
            for (int nl = 0; nl < 3; ++nl) {
                const int row = (wave * 3 + nl) * 16 + lr;
                const int cb = h * 4 + lg;
                const bf16x8 b = *(const bf16x8*)&ws[cur][row * 64 + ((cb ^ (row & 7)) << 3)];
                acc[0][nl] = MFMA(a[0], b, acc[0][nl]);
                acc[1][nl] = MFMA(a[1], b, acc[1][nl]);
            }
        }
        __syncthreads();
    }

    const float SCQ = 0.0450842200277801f;   // log2(e)/sqrt(1024)
    const int bb = m0 >> 11;
    const int tb = m0 & 2047;
#pragma unroll
    for (int mm = 0; mm < 2; ++mm)
#pragma unroll
        for (int nl = 0; nl < 3; ++nl) {
            const int col = (wave * 3 + nl) * 16 + lr;
            const int rl = mm * 16 + lg * 4;
            if (col < 64) {
#pragma unroll
                for (int r = 0; r < 4; ++r)
                    qo[(size_t)(m0 + rl + r) * 64 + col] = f2bf(acc[mm][nl][r] * SCQ);
            } else if (col < 128) {
#pragma unroll
                for (int r = 0; r < 4; ++r)
                    ko[(size_t)(m0 + rl + r) * 64 + (col - 64)] = f2bf(acc[mm][nl][r]);
            } else {
                u16x4 pk;
#pragma unroll
                for (int r = 0; r < 4; ++r) pk[r] = f2bf(acc[mm][nl][r]);
                *(u16x4*)&vT[(size_t)(bb * 64 + (col - 128)) * 2048 + tb + rl] = pk;
            }
        }
}

// ---------------------------------------------------------------------------
// Kernel 3: causal attention. R11 shape (128 q-rows/block, 32/wave in two
// sub-phases) but with SEPARATE lP buffers per sub-phase -> the two per-tile
// dependency chains are fully independent and can interleave (chain-ILP).
// 320 blocks, heavy-first, fixed-max softmax, bf16 partials.
// LDS 50.4KB -> 3 blocks/CU.
// ---------------------------------------------------------------------------
#define PPITCH 72
__global__ __launch_bounds__(256, 3) void attn_part(const u16* __restrict__ q,
                                                    const u16* __restrict__ k,
                                                    const u16* __restrict__ vT,
                                                    u16* __restrict__ Opb,
                                                    float* __restrict__ Lp) {
    const int b = blockIdx.x & 7;
    int g = blockIdx.x >> 3;                  // 0..39, heavy-first
    int qt = 15, rem = g;
    while (rem >= (qt >> 2) + 1) { rem -= (qt >> 2) + 1; --qt; }
    const int c0 = rem;
    const int q0 = qt * 128;
    const int kv_lo = c0 * 512;
    const int kv_hi = min(kv_lo + 512, q0 + 128);
    const int ntiles = (kv_hi - kv_lo) >> 6;
    const int slot = (b * 16 + qt) * 4 + c0;

    __shared__ __align__(16) u16 lK[2][64 * 64];        // 8KB each
    __shared__ __align__(16) u16 lV[2][64 * 64];        // 8KB each
    __shared__ __align__(16) u16 lP[2][4][16 * PPITCH]; // per-(h,wave) P: independent chains

    const int tid = threadIdx.x;
    const int wave = tid >> 6, lane = tid & 63;
    const int lr = lane & 15, lg = lane >> 4;

    const u16* qb = q + (size_t)b * 2048 * 64;
    const u16* kb = k + (size_t)b * 2048 * 64;
    const u16* vb = vT + (size_t)b * 64 * 2048;

    const int rbase = q0 + wave * 32;
    bf16x8 qf[2][2];
#pragma unroll
    for (int h = 0; h < 2; ++h) {
        const u16* qp = qb + (size_t)(rbase + h * 16 + lr) * 64 + lg * 8;
        qf[h][0] = *(const bf16x8*)(qp);
        qf[h][1] = *(const bf16x8*)(qp + 32);
    }

    f32x4 oacc[2][4];
#pragma unroll
    for (int h = 0; h < 2; ++h)
#pragma unroll
        for (int n = 0; n < 4; ++n) oacc[h][n] = (f32x4){0.f, 0.f, 0.f, 0.f};
    float rs[2] = {0.f, 0.f};

#define ASTAGE(bufi, kv0_)                                                             \
    {                                                                                  \
        _Pragma("unroll") for (int j = 0; j < 2; ++j) {                                \
            const int cid = j * 256 + wave * 64 + lane;                                \
            const int row = cid >> 3, cc = cid & 7;                                    \
            load_lds16(kb + (size_t)((kv0_) + row) * 64 + ((cc ^ (row & 7)) << 3),     \
                       &lK[bufi][(j * 256 + wave * 64) * 8]);                          \
            load_lds16(vb + (size_t)row * 2048 + (kv0_) + ((cc ^ (row & 7)) << 3),     \
                       &lV[bufi][(j * 256 + wave * 64) * 8]);                          \
        }                                                                              \
    }

    ASTAGE(0, kv_lo);
    __syncthreads();

    for (int it = 0; it < ntiles; ++it) {
        const int cur = it & 1;
        if (it + 1 < ntiles) ASTAGE(cur ^ 1, kv_lo + (it + 1) * 64);

        const int kv0 = kv_lo + it * 64;
        // how many sub-phases are live this tile (wave-uniform)
        const int nh = (kv0 <= rbase + 15) ? ((kv0 <= rbase + 31) ? 2 : 1) : 0;
        // note: kv0 <= rbase+15 -> h=0 live; kv0 <= rbase+31 -> h=1 live.
        // h=1 live implies h=0 live (rbase+31 > rbase+15), so nh in {0,1,2} with
        // nh==1 meaning ONLY h=0?? -- careful: h=1 condition is LOOSER. Fix below.

        // h=0 live iff kv0 <= rbase+15; h=1 live iff kv0 <= rbase+31.
        const bool live0 = (kv0 <= rbase + 15);
        const bool live1 = (kv0 <= rbase + 31);
        (void)nh;

        if (live1) {
            // ---- S^T for both sub-phases (independent MFMA chains)
            f32x4 s0[4], s1[4];
#pragma unroll
            for (int n = 0; n < 4; ++n) {
                const int row = n * 16 + lr;
                const bf16x8 kf0 = *(const bf16x8*)&lK[cur][row * 64 + ((lg ^ (row & 7)) << 3)];
                const bf16x8 kf1 =
                    *(const bf16x8*)&lK[cur][row * 64 + (((4 + lg) ^ (row & 7)) << 3)];
                if (live0) {
                    f32x4 a = (f32x4){0.f, 0.f, 0.f, 0.f};
                    a = MFMA(kf0, qf[0][0], a);
                    a = MFMA(kf1, qf[0][1], a);
                    s0[n] = a;
                }
                f32x4 c = (f32x4){0.f, 0.f, 0.f, 0.f};
                c = MFMA(kf0, qf[1][0], c);
                c = MFMA(kf1, qf[1][1], c);
                s1[n] = c;
            }

            // ---- softmax + P store, both chains (separate buffers)
            const int myrow0 = rbase + lr;
            const int myrow1 = rbase + 16 + lr;
            const bool msk0 = (kv0 + 63 > rbase);
            const bool msk1 = (kv0 + 63 > rbase + 16);
#pragma unroll
            for (int n = 0; n < 4; ++n) {
                const int kvn = kv0 + n * 16 + lg * 4;
                if (live0) {
                    u16x4 pk;
#pragma unroll
                    for (int r = 0; r < 4; ++r) {
                        const float p =
                            (!msk0 || kvn + r <= myrow0) ? exp2f(s0[n][r]) : 0.f;
                        rs[0] += p;
                        pk[r] = f2bf(p);
                    }
                    *(u16x4*)&lP[0][wave][lr * PPITCH + n * 16 + lg * 4] = pk;
                }
                {
                    u16x4 pk;
#pragma unroll
                    for (int r = 0; r < 4; ++r) {
                        const float p =
                            (!msk1 || kvn + r <= myrow1) ? exp2f(s1[n][r]) : 0.f;
                        rs[1] += p;
                        pk[r] = f2bf(p);
                    }
                    *(u16x4*)&lP[1][wave][lr * PPITCH + n * 16 + lg * 4] = pk;
                }
            }

            // ---- PV, both chains
#pragma unroll
            for (int kc = 0; kc < 2; ++kc) {
                const bf16x8 pf0 =
                    *(const bf16x8*)&lP[0][wave][lr * PPITCH + kc * 32 + lg * 8];
                const bf16x8 pf1 =
                    *(const bf16x8*)&lP[1][wave][lr * PPITCH + kc * 32 + lg * 8];
#pragma unroll
                for (int n = 0; n < 4; ++n) {
                    const int row = n * 16 + lr;
                    const bf16x8 vf =
                        *(const bf16x8*)&lV[cur][row * 64 + (((kc * 4 + lg) ^ (row & 7)) << 3)];
                    if (live0) oacc[0][n] = MFMA(pf0, vf, oacc[0][n]);
                    oacc[1][n] = MFMA(pf1, vf, oacc[1][n]);
                }
            }
        }
        __syncthreads();
    }

    // ---- row sums + bf16 partials (MFMA-native layout)
#pragma unroll
    for (int h = 0; h < 2; ++h) {
        rs[h] += __shfl_xor(rs[h], 16);
        rs[h] += __shfl_xor(rs[h], 32);
        if (lane < 16) Lp[slot * 128 + wave * 32 + h * 16 + lr] = rs[h];
    }

    u16* op = Opb + (size_t)slot * 8192 + wave * 2048;
#pragma unroll
    for (int h = 0; h < 2; ++h)
#pragma unroll
        for (int n = 0; n < 4; ++n)
#pragma unroll
            for (int r = 0; r < 4; ++r)
                op[h * 1024 + n * 256 + (lg * 4 + r) * 16 + lr] = f2bf(oacc[h][n][r]);
}

// ---------------------------------------------------------------------------
// Kernel 4: merge <=4 kv-chunk partials (plain sums; fixed max) + normalize.
// ---------------------------------------------------------------------------
__global__ __launch_bounds__(256) void attn_combine(const u16* __restrict__ Opb,
                                                    const float* __restrict__ Lp,
                                                    float* __restrict__ out) {
    const int gid = blockIdx.x * 256 + threadIdx.x;   // 1048576
    const int col = gid & 63;
    const int row = gid >> 6;            // b*2048 + t
    const int b = row >> 11, tt = row & 2047;
    const int qt = tt >> 7, i = tt & 127;
    const int nc = (qt >> 2) + 1;
    const size_t sbase = (size_t)(b * 16 + qt) * 4;
    const int sub = (i >> 5) * 2048 + ((i >> 4) & 1) * 1024 + (col >> 4) * 256 +
                    (i & 15) * 16 + (col & 15);

    float O = 0.f, L = 0.f;
    for (int c = 0; c < nc; ++c) {
        O += bf2f(Opb[(sbase + c) * 8192 + sub]);
        L += Lp[(sbase + c) * 128 + i];
    }
    out[(size_t)row * 64 + col] = O / L;
}

// ---------------------------------------------------------------------------
extern "C" void kernel_launch(void* const* d_in, const int* in_sizes, int n_in,
                              void* d_out, int out_size, void* d_ws, size_t ws_size,
                              hipStream_t stream) {
    const float* x = (const float*)d_in[0];
    const float* Wq = (const float*)d_in[1];
    const float* Wk = (const float*)d_in[2];
    const float* Wv = (const float*)d_in[3];
    float* out = (float*)d_out;

    char* ws = (char*)d_ws;
    u16* Wtt = (u16*)ws;                                  // 384 KB @ 0
    u16* qb = (u16*)(ws + (512 << 10));                   // 2 MB
    u16* kb = (u16*)(ws + (512 << 10) + (2 << 20));       // 2 MB
    u16* vT = (u16*)(ws + (512 << 10) + (4 << 20));       // 2 MB
    u16* Opb = (u16*)(ws + (8 << 20));                    // 8.4 MB
    float* Lp = (float*)(ws + (20 << 20));                // 256 KB

    wt_pack<<<1024, 192, 0, stream>>>(Wq, Wk, Wv, Wtt);
    qkv_gemm<<<512, 256, 0, stream>>>(x, Wtt, qb, kb, vT);
    attn_part<<<320, 256, 0, stream>>>(qb, kb, vT, Opb, Lp);
    attn_combine<<<4096, 256, 0, stream>>>(Opb, Lp, out);
}

// Round 13
// 54.992 us; speedup vs baseline: 1.1172x; 1.1172x over previous
//
#include <hip/hip_runtime.h>

typedef unsigned short u16;
typedef __attribute__((ext_vector_type(4))) float f32x4;
typedef __attribute__((ext_vector_type(8))) short bf16x8;
typedef __attribute__((ext_vector_type(4))) u16 u16x4;
typedef __attribute__((ext_vector_type(8))) u16 u16x8;

#define MFMA(a, b, c) __builtin_amdgcn_mfma_f32_16x16x32_bf16(a, b, c, 0, 0, 0)

__device__ __forceinline__ u16 f2bf(float f) {
    unsigned u = __float_as_uint(f);
    u += 0x7fffu + ((u >> 16) & 1u);   // round-to-nearest-even
    return (u16)(u >> 16);
}
__device__ __forceinline__ float bf2f(u16 h) {
    unsigned u = ((unsigned)h) << 16;
    return __uint_as_float(u);
}

__device__ __forceinline__ void load_lds16(const void* g, void* l) {
    __builtin_amdgcn_global_load_lds((const __attribute__((address_space(1))) void*)g,
                                     (__attribute__((address_space(3))) void*)l,
                                     16, 0, 0);
}

// ---------------------------------------------------------------------------
// Kernel 1: pack Wq|Wk|Wv (fp32 [1024][64]) -> Wtt bf16, tile-major + swizzled.
// ---------------------------------------------------------------------------
__global__ void wt_pack(const float* __restrict__ Wq, const float* __restrict__ Wk,
                        const float* __restrict__ Wv, u16* __restrict__ Wtt) {
    const int k = blockIdx.x;        // 0..1023
    const int n = threadIdx.x;       // 0..191
    const float* W = (n < 64) ? Wq : (n < 128 ? Wk : Wv);
    const float v = W[(size_t)k * 64 + (n & 63)];
    const int kt = k >> 6, ks = k & 63, c = ks >> 3, ci = ks & 7;
    Wtt[(size_t)kt * 12288 + n * 64 + (((c ^ (n & 7)) << 3) + ci)] = f2bf(v);
}

// ---------------------------------------------------------------------------
// Kernel 2: qkv projection, m97-structure, BM=32 / 4 waves / 512 blocks.
// Q output pre-scaled by log2(e)/sqrt(1024). (Best-known config, unchanged.)
// ---------------------------------------------------------------------------
__global__ __launch_bounds__(256, 2) void qkv_gemm(const float* __restrict__ x,
                                                   const u16* __restrict__ Wtt,
                                                   u16* __restrict__ qo,
                                                   u16* __restrict__ ko,
                                                   u16* __restrict__ vT) {
    const int tid = threadIdx.x;
    const int lane = tid & 63, wave = tid >> 6;
    const int lr = lane & 15, lg = lane >> 4;
    const int m0 = blockIdx.x * 32;

    __shared__ __align__(16) float xs[2][32 * 64];
    __shared__ __align__(16) u16 ws[2][192 * 64];

    f32x4 acc[2][3];
#pragma unroll
    for (int m = 0; m < 2; ++m)
#pragma unroll
        for (int n = 0; n < 3; ++n) acc[m][n] = (f32x4){0.f, 0.f, 0.f, 0.f};

    const int srow = tid >> 4;
    const int schk = tid & 15;

    {
#pragma unroll
        for (int j = 0; j < 2; ++j) {
            const int rr = j * 16 + srow;
            const float* src = x + (size_t)(m0 + rr) * 1024 + ((schk ^ (rr & 7)) << 2);
            load_lds16(src, &xs[0][j * 1024 + wave * 256]);
        }
#pragma unroll
        for (int j = 0; j < 6; ++j) {
            const u16* src = Wtt + (size_t)j * 2048 + tid * 8;
            load_lds16(src, &ws[0][j * 2048 + wave * 512]);
        }
    }
    __syncthreads();

    for (int kt = 0; kt < 16; ++kt) {
        const int cur = kt & 1;
        if (kt < 15) {
            const int nxt = cur ^ 1;
#pragma unroll
            for (int j = 0; j < 2; ++j) {
                const int rr = j * 16 + srow;
                const float* src =
                    x + (size_t)(m0 + rr) * 1024 + (kt + 1) * 64 + ((schk ^ (rr & 7)) << 2);
                load_lds16(src, &xs[nxt][j * 1024 + wave * 256]);
            }
#pragma unroll
            for (int j = 0; j < 6; ++j) {
                const u16* src = Wtt + (size_t)(kt + 1) * 12288 + j * 2048 + tid * 8;
                load_lds16(src, &ws[nxt][j * 2048 + wave * 512]);
            }
        }
#pragma unroll
        for (int h = 0; h < 2; ++h) {
            bf16x8 a[2];
#pragma unroll
            for (int mm = 0; mm < 2; ++mm) {
                const int rr = mm * 16 + lr;
                const int c0 = h * 8 + lg * 2;
                f32x4 f0 = *(const f32x4*)&xs[cur][rr * 64 + ((c0 ^ (rr & 7)) << 2)];
                f32x4 f1 = *(const f32x4*)&xs[cur][rr * 64 + (((c0 + 1) ^ (rr & 7)) << 2)];
                bf16x8 t;
#pragma unroll
                for (int i = 0; i < 4; ++i) {
                    t[i] = (short)f2bf(f0[i]);
                    t[i + 4] = (short)f2bf(f1[i]);
                }
                a[mm] = t;
            }
#pragma unroll
            for (int nl = 0; nl < 3; ++nl) {
                const int row = (wave * 3 + nl) * 16 + lr;
                const int cb = h * 4 + lg;
                const bf16x8 b = *(const bf16x8*)&ws[cur][row * 64 + ((cb ^ (row & 7)) << 3)];
                acc[0][nl] = MFMA(a[0], b, acc[0][nl]);
                acc[1][nl] = MFMA(a[1], b, acc[1][nl]);
            }
        }
        __syncthreads();
    }

    const float SCQ = 0.0450842200277801f;   // log2(e)/sqrt(1024)
    const int bb = m0 >> 11;
    const int tb = m0 & 2047;
#pragma unroll
    for (int mm = 0; mm < 2; ++mm)
#pragma unroll
        for (int nl = 0; nl < 3; ++nl) {
            const int col = (wave * 3 + nl) * 16 + lr;
            const int rl = mm * 16 + lg * 4;
            if (col < 64) {
#pragma unroll
                for (int r = 0; r < 4; ++r)
                    qo[(size_t)(m0 + rl + r) * 64 + col] = f2bf(acc[mm][nl][r] * SCQ);
            } else if (col < 128) {
#pragma unroll
                for (int r = 0; r < 4; ++r)
                    ko[(size_t)(m0 + rl + r) * 64 + (col - 64)] = f2bf(acc[mm][nl][r]);
            } else {
                u16x4 pk;
#pragma unroll
                for (int r = 0; r < 4; ++r) pk[r] = f2bf(acc[mm][nl][r]);
                *(u16x4*)&vT[(size_t)(bb * 64 + (col - 128)) * 2048 + tb + rl] = pk;
            }
        }
}

// ---------------------------------------------------------------------------
// Kernel 3: causal attention — EXACT R7 structure (best known: 57.1us total):
// 2-phase global_load_lds dbuf, 640 blocks, 64 q-rows/block, 3 blocks/CU.
// Only change: bf16 partials in MFMA-native layout (halved partial traffic).
// ---------------------------------------------------------------------------
#define PPITCH 72
__global__ __launch_bounds__(256, 3) void attn_part(const u16* __restrict__ q,
                                                    const u16* __restrict__ k,
                                                    const u16* __restrict__ vT,
                                                    u16* __restrict__ Opb,
                                                    float* __restrict__ Lp) {
    const int b = blockIdx.x & 7;
    int g = blockIdx.x >> 3;                  // 0..79, heavy-first
    int qt = 31, rem = g;
    while (rem >= (qt >> 3) + 1) { rem -= (qt >> 3) + 1; --qt; }
    const int c0 = rem;
    const int q0 = qt * 64;
    const int kv_lo = c0 * 512;
    const int kv_hi = min(kv_lo + 512, q0 + 64);
    const int ntiles = (kv_hi - kv_lo) >> 6;
    const int slot = (b * 32 + qt) * 4 + c0;

    __shared__ __align__(16) u16 lK[2][64 * 64];     // 8KB each
    __shared__ __align__(16) u16 lV[2][64 * 64];     // 8KB each
    __shared__ __align__(16) u16 lP[4][16 * PPITCH]; // per-wave P

    const int tid = threadIdx.x;
    const int wave = tid >> 6, lane = tid & 63;
    const int lr = lane & 15, lg = lane >> 4;

    const u16* qb = q + (size_t)b * 2048 * 64;
    const u16* kb = k + (size_t)b * 2048 * 64;
    const u16* vb = vT + (size_t)b * 64 * 2048;

    const int myrow = q0 + wave * 16 + lr;
    const bf16x8 qf0 = *(const bf16x8*)(qb + (size_t)myrow * 64 + lg * 8);
    const bf16x8 qf1 = *(const bf16x8*)(qb + (size_t)myrow * 64 + 32 + lg * 8);

    f32x4 oacc[4];
#pragma unroll
    for (int n = 0; n < 4; ++n) oacc[n] = (f32x4){0.f, 0.f, 0.f, 0.f};
    float rs = 0.f;

#define ASTAGE(bufi, kv0_)                                                             \
    {                                                                                  \
        _Pragma("unroll") for (int j = 0; j < 2; ++j) {                                \
            const int cid = j * 256 + wave * 64 + lane;                                \
            const int row = cid >> 3, cc = cid & 7;                                    \
            load_lds16(kb + (size_t)((kv0_) + row) * 64 + ((cc ^ (row & 7)) << 3),     \
                       &lK[bufi][(j * 256 + wave * 64) * 8]);                          \
            load_lds16(vb + (size_t)row * 2048 + (kv0_) + ((cc ^ (row & 7)) << 3),     \
                       &lV[bufi][(j * 256 + wave * 64) * 8]);                          \
        }                                                                              \
    }

    ASTAGE(0, kv_lo);
    __syncthreads();

    for (int it = 0; it < ntiles; ++it) {
        const int cur = it & 1;
        if (it + 1 < ntiles) ASTAGE(cur ^ 1, kv_lo + (it + 1) * 64);

        const int kv0 = kv_lo + it * 64;
        if (kv0 <= q0 + wave * 16 + 15) {      // wave-uniform causal guard
            f32x4 s[4];
#pragma unroll
            for (int n = 0; n < 4; ++n) {
                const int row = n * 16 + lr;
                const bf16x8 kf0 = *(const bf16x8*)&lK[cur][row * 64 + ((lg ^ (row & 7)) << 3)];
                const bf16x8 kf1 =
                    *(const bf16x8*)&lK[cur][row * 64 + (((4 + lg) ^ (row & 7)) << 3)];
                f32x4 a = (f32x4){0.f, 0.f, 0.f, 0.f};
                a = MFMA(kf0, qf0, a);
                a = MFMA(kf1, qf1, a);
                s[n] = a;   // S^T: rows kv = 16n+lg*4+r, col q = lr
            }

            const bool msk = (kv0 + 63 > q0 + wave * 16);
#pragma unroll
            for (int n = 0; n < 4; ++n) {
                u16x4 pk;
#pragma unroll
                for (int r = 0; r < 4; ++r) {
                    const int kvi = kv0 + n * 16 + lg * 4 + r;
                    const float p = (!msk || kvi <= myrow) ? exp2f(s[n][r]) : 0.f;
                    rs += p;
                    pk[r] = f2bf(p);
                }
                *(u16x4*)&lP[wave][lr * PPITCH + n * 16 + lg * 4] = pk;
            }

#pragma unroll
            for (int kc = 0; kc < 2; ++kc) {
                const bf16x8 pf = *(const bf16x8*)&lP[wave][lr * PPITCH + kc * 32 + lg * 8];
#pragma unroll
                for (int n = 0; n < 4; ++n) {
                    const int row = n * 16 + lr;
                    const bf16x8 vf =
                        *(const bf16x8*)&lV[cur][row * 64 + (((kc * 4 + lg) ^ (row & 7)) << 3)];
                    oacc[n] = MFMA(pf, vf, oacc[n]);
                }
            }
        }
        __syncthreads();
    }

    // ---- row-sum across the 4 lanes sharing lr
    rs += __shfl_xor(rs, 16);
    rs += __shfl_xor(rs, 32);
    if (lane < 16) Lp[slot * 64 + wave * 16 + lr] = rs;

    // ---- bf16 partials, MFMA-native layout: sub = (i>>4)*1024+(col>>4)*256+(i&15)*16+(col&15)
    u16* op = Opb + (size_t)slot * 4096 + wave * 1024;
#pragma unroll
    for (int n = 0; n < 4; ++n)
#pragma unroll
        for (int r = 0; r < 4; ++r)
            op[n * 256 + (lg * 4 + r) * 16 + lr] = f2bf(oacc[n][r]);
}

// ---------------------------------------------------------------------------
// Kernel 4: vectorized merge. Thread owns 8 consecutive cols of one row:
// per chunk ONE u16x8 (16B) load + scalar Lp; two f32x4 stores.
// 131072 threads = 512 blocks.
// ---------------------------------------------------------------------------
__global__ __launch_bounds__(256) void attn_combine(const u16* __restrict__ Opb,
                                                    const float* __restrict__ Lp,
                                                    float* __restrict__ out) {
    const int gid = blockIdx.x * 256 + threadIdx.x;   // 131072
    const int colg = gid & 7;
    const int row = gid >> 3;            // b*2048 + t
    const int b = row >> 11, tt = row & 2047;
    const int qt = tt >> 6, i = tt & 63;
    const int nc = (qt >> 3) + 1;
    const size_t sbase = (size_t)(b * 32 + qt) * 4;
    const int sub0 = (i >> 4) * 1024 + (colg >> 1) * 256 + (i & 15) * 16 + (colg & 1) * 8;

    float O[8] = {0.f, 0.f, 0.f, 0.f, 0.f, 0.f, 0.f, 0.f};
    float L = 0.f;
    for (int c = 0; c < nc; ++c) {
        const u16x8 v = *(const u16x8*)&Opb[(sbase + c) * 4096 + sub0];
#pragma unroll
        for (int j = 0; j < 8; ++j) O[j] += bf2f(v[j]);
        L += Lp[(sbase + c) * 64 + i];
    }
    const float rinv = 1.0f / L;
    f32x4 o0, o1;
#pragma unroll
    for (int j = 0; j < 4; ++j) {
        o0[j] = O[j] * rinv;
        o1[j] = O[4 + j] * rinv;
    }
    float* ob = out + (size_t)row * 64 + colg * 8;
    *(f32x4*)(ob) = o0;
    *(f32x4*)(ob + 4) = o1;
}

// ---------------------------------------------------------------------------
extern "C" void kernel_launch(void* const* d_in, const int* in_sizes, int n_in,
                              void* d_out, int out_size, void* d_ws, size_t ws_size,
                              hipStream_t stream) {
    const float* x = (const float*)d_in[0];
    const float* Wq = (const float*)d_in[1];
    const float* Wk = (const float*)d_in[2];
    const float* Wv = (const float*)d_in[3];
    float* out = (float*)d_out;

    char* ws = (char*)d_ws;
    u16* Wtt = (u16*)ws;                                  // 384 KB @ 0
    u16* qb = (u16*)(ws + (512 << 10));                   // 2 MB
    u16* kb = (u16*)(ws + (512 << 10) + (2 << 20));       // 2 MB
    u16* vT = (u16*)(ws + (512 << 10) + (4 << 20));       // 2 MB
    u16* Opb = (u16*)(ws + (8 << 20));                    // 1024*4096*2 = 8.4 MB
    float* Lp = (float*)(ws + (20 << 20));                // 1024*64*4 = 256 KB

    wt_pack<<<1024, 192, 0, stream>>>(Wq, Wk, Wv, Wtt);
    qkv_gemm<<<512, 256, 0, stream>>>(x, Wtt, qb, kb, vT);
    attn_part<<<640, 256, 0, stream>>>(qb, kb, vT, Opb, Lp);
    attn_combine<<<512, 256, 0, stream>>>(Opb, Lp, out);
}